// Round 23
// baseline (97.385 us; speedup 1.0000x reference)
//
#include <hip/hip_runtime.h>

typedef short bf8 __attribute__((ext_vector_type(8)));   // 8 bf16 in 4 VGPRs
typedef float f32x4 __attribute__((ext_vector_type(4)));
typedef float f32x16 __attribute__((ext_vector_type(16)));
typedef int i32x4 __attribute__((ext_vector_type(4)));

__device__ __forceinline__ ushort f2b(float f) {
  unsigned x = __builtin_bit_cast(unsigned, f);
  unsigned r = (x + 0x7fffu + ((x >> 16) & 1u)) >> 16;
  return (ushort)r;
}
__device__ __forceinline__ float b2f(ushort u) {
  unsigned x = ((unsigned)u) << 16;
  return __builtin_bit_cast(float, x);
}

__device__ __forceinline__ f32x4 mfma16(bf8 a, bf8 b, f32x4 c) {
  return __builtin_amdgcn_mfma_f32_16x16x32_bf16(a, b, c, 0, 0, 0);
}
__device__ __forceinline__ f32x16 mfma32(bf8 a, bf8 b, f32x16 c) {
  return __builtin_amdgcn_mfma_f32_32x32x16_bf16(a, b, c, 0, 0, 0);
}

__device__ __forceinline__ float fexp2(float x) {
#if __has_builtin(__builtin_amdgcn_exp2f)
  return __builtin_amdgcn_exp2f(x);
#else
  return exp2f(x);
#endif
}

__device__ __forceinline__ uint cvtpk(float lo, float hi_) {
  uint r;
  asm("v_cvt_pk_bf16_f32 %0, %1, %2" : "=v"(r) : "v"(lo), "v"(hi_));
  return r;
}
__device__ __forceinline__ void plswap(uint& a, uint& b) {
  asm("v_permlane32_swap_b32 %0, %1" : "+v"(a), "+v"(b));
}

__device__ __forceinline__ void gload16(const ushort* g, ushort* l) {
  __builtin_amdgcn_global_load_lds(
      (const __attribute__((address_space(1))) void*)g,
      (__attribute__((address_space(3))) void*)l, 16, 0, 0);
}

// ---------------- prep1: cast x (f32->bf16) + all weight transposes ------
__global__ __launch_bounds__(256) void prep1(
    const float* __restrict__ x, const float* __restrict__ wq,
    const float* __restrict__ wk, const float* __restrict__ wv,
    const float* __restrict__ wo, ushort* __restrict__ xb,
    ushort* __restrict__ wqkvT, ushort* __restrict__ woT) {
  __shared__ float tile[32][33];
  const int bid = blockIdx.x;
  if (bid < 4096) {
    const int i = (bid * 256 + threadIdx.x) * 4;
    float4 v = *(const float4*)(x + i);
    ushort4 o;
    o.x = f2b(v.x); o.y = f2b(v.y); o.z = f2b(v.z); o.w = f2b(v.w);
    *(ushort4*)(xb + i) = o;
    return;
  }
  int t = bid - 4096;  // 0..2559
  const float* src;
  ushort* dst;
  int N;
  if (t < 1024) {
    src = wq; dst = wqkvT; N = 1024;
  } else if (t < 1280) {
    src = wk; dst = wqkvT + 1024 * 1024; N = 256; t -= 1024;
  } else if (t < 1536) {
    src = wv; dst = wqkvT + 1280 * 1024; N = 256; t -= 1280;
  } else {
    src = wo; dst = woT; N = 1024; t -= 1536;
  }
  const int kx = (t & 31) * 32, nx = (t >> 5) * 32;
  const int tx = threadIdx.x & 31, ty = threadIdx.x >> 5;
#pragma unroll
  for (int i = ty; i < 32; i += 8)
    tile[i][tx] = src[(size_t)(kx + i) * N + nx + tx];
  __syncthreads();
#pragma unroll
  for (int i = ty; i < 32; i += 8)
    dst[(size_t)(nx + i) * 1024 + kx + tx] = f2b(tile[tx][i]);
}

// ------- gemm_rope: x @ wqkvT with FUSED RoPE + V-transpose epilogue ------
__global__ __launch_bounds__(256) void gemm_rope(
    const ushort* __restrict__ A, const ushort* __restrict__ Bt,
    const float* __restrict__ fc, const float* __restrict__ fs,
    ushort* __restrict__ qh, ushort* __restrict__ kh,
    ushort* __restrict__ vT) {
  __shared__ ushort aL[2][64 * 64];    // 2 x 8 KB
  __shared__ ushort bL[2][128 * 64];   // 2 x 16 KB (reused for V transpose)
  const int K = 1024;
  const int tid = threadIdx.x;
  const int wid = tid >> 6, lane = tid & 63;
  const int l15 = lane & 15, l4 = lane >> 4;
  const int qch = gridDim.x >> 3;
  const int sw = (blockIdx.x & 7) * qch + (blockIdx.x >> 3);
  const int bxi = sw % 12, byi = sw / 12;
  const int bm = byi * 64, bn = bxi * 128;
  const int wr = (wid & 1) * 32, wc = (wid >> 1) * 64;
  const int nIter = K >> 6;

  auto stage = [&](int it, int par) {
    const int kb = it * 64;
#pragma unroll
    for (int i = 0; i < 2; ++i) {
      const int e = (i * 256 + tid) * 8;
      const int r = e >> 6, c = e & 63;
      gload16(A + (size_t)(bm + r) * K + kb + c,
              &aL[par][i * 2048 + wid * 512]);
    }
#pragma unroll
    for (int i = 0; i < 4; ++i) {
      const int e = (i * 256 + tid) * 8;
      const int r = e >> 6, c = e & 63;
      gload16(Bt + (size_t)(bn + r) * K + kb + c,
              &bL[par][i * 2048 + wid * 512]);
    }
  };

  stage(0, 0);
  f32x4 acc[2][4] = {};
  for (int it = 0; it < nIter; ++it) {
    const int par = it & 1;
    asm volatile("s_waitcnt vmcnt(0)" ::: "memory");
    __builtin_amdgcn_s_barrier();
    asm volatile("" ::: "memory");
    if (it + 1 < nIter) stage(it + 1, par ^ 1);
    bf8 af[2][2], bfr[4][2];
#pragma unroll
    for (int i = 0; i < 2; ++i)
#pragma unroll
      for (int kk = 0; kk < 2; ++kk)
        af[i][kk] =
            *(const bf8*)&aL[par][(wr + i * 16 + l15) * 64 + kk * 32 + l4 * 8];
#pragma unroll
    for (int j = 0; j < 4; ++j)
#pragma unroll
      for (int kk = 0; kk < 2; ++kk)
        bfr[j][kk] =
            *(const bf8*)&bL[par][(wc + j * 16 + l15) * 64 + kk * 32 + l4 * 8];
#pragma unroll
    for (int kk = 0; kk < 2; ++kk)
#pragma unroll
      for (int i = 0; i < 2; ++i)
#pragma unroll
        for (int j = 0; j < 4; ++j)
          acc[i][j] = mfma16(af[i][kk], bfr[j][kk], acc[i][j]);
  }

  if (bxi < 10) {
    // ---- Q or K: fused RoPE, direct write ----
    const bool isQ = bxi < 8;
    const float qs = isQ ? 0.18033688f : 1.0f;  // (1/8)*log2(e) for Q
    const int colbase = bn + wc;
    const int head = isQ ? (colbase >> 6) : ((colbase - 1024) >> 6);
    const int nh = isQ ? 16 : 4;
    ushort* outp = isQ ? qh : kh;
#pragma unroll
    for (int i = 0; i < 2; ++i)
#pragma unroll
      for (int j = 0; j < 4; ++j) {
        const int d = j * 16 + l15;
        const int d2 = d >> 1;
#pragma unroll
        for (int r = 0; r < 4; ++r) {
          const int row = bm + wr + i * 16 + l4 * 4 + r;
          const int s = row & 2047, bb = row >> 11;
          const float c = fc[s * 32 + d2], sn = fs[s * 32 + d2];
          const float val = acc[i][j][r];
          const float par = __shfl_xor(val, 1);
          float o;
          if ((l15 & 1) == 0)
            o = (val * c - par * sn) * qs;  // even d: tr*c - ti*s
          else
            o = (par * sn + val * c) * qs;  // odd d: tr*s + ti*c
          outp[((size_t)(bb * nh + head) * 2048 + s) * 64 + d] = f2b(o);
        }
      }
  } else {
    // ---- V: LDS transpose (reuse bL, free after K-loop) then write vT ----
    __syncthreads();  // block-uniform branch; all frag reads already in regs
    ushort* ldsT = &bL[0][0];  // 128 x 68 ushorts = 17 KB <= 32 KB
#pragma unroll
    for (int i = 0; i < 2; ++i)
#pragma unroll
      for (int j = 0; j < 4; ++j) {
        const int cl = wc + j * 16 + l15;
#pragma unroll
        for (int r = 0; r < 4; ++r) {
          const int rl = wr + i * 16 + l4 * 4 + r;
          ldsT[cl * 68 + rl] = f2b(acc[i][j][r]);
        }
      }
    __syncthreads();
    const int bb = bm >> 11, sbase = bm & 2047;
    const int dl = tid >> 1, sh = (tid & 1) * 32;
    const int gcol = bn + dl - 1280;
    const int kv = gcol >> 6, d = gcol & 63;
    ushort* dst = vT + ((size_t)(bb * 4 + kv) * 64 + d) * 2048 + sbase + sh;
    const ushort* srcl = ldsT + dl * 68 + sh;
#pragma unroll
    for (int k = 0; k < 8; ++k)
      *(uint2*)(dst + k * 4) = *(const uint2*)(srcl + k * 4);
  }
}

// ------- GEMM C[M][N]=A[M][K]*Bt[N][K]^T; 64x128, BK=64, double-buffered --
template <bool OUT_BF16>
__global__ __launch_bounds__(256) void gemm_bt(const ushort* __restrict__ A,
                                               const ushort* __restrict__ Bt,
                                               void* __restrict__ Cv, int M,
                                               int N, int K, int nbx) {
  __shared__ ushort aL[2][64 * 64];    // 2 x 8 KB
  __shared__ ushort bL[2][128 * 64];   // 2 x 16 KB
  const int tid = threadIdx.x;
  const int wid = tid >> 6, lane = tid & 63;
  const int l15 = lane & 15, l4 = lane >> 4;
  const int qch = gridDim.x >> 3;
  const int sw = (blockIdx.x & 7) * qch + (blockIdx.x >> 3);
  const int bxi = sw % nbx, byi = sw / nbx;
  const int bm = byi * 64, bn = bxi * 128;
  const int wr = (wid & 1) * 32, wc = (wid >> 1) * 64;
  const int nIter = K >> 6;

  auto stage = [&](int it, int par) {
    const int kb = it * 64;
#pragma unroll
    for (int i = 0; i < 2; ++i) {
      const int e = (i * 256 + tid) * 8;
      const int r = e >> 6, c = e & 63;
      gload16(A + (size_t)(bm + r) * K + kb + c,
              &aL[par][i * 2048 + wid * 512]);
    }
#pragma unroll
    for (int i = 0; i < 4; ++i) {
      const int e = (i * 256 + tid) * 8;
      const int r = e >> 6, c = e & 63;
      gload16(Bt + (size_t)(bn + r) * K + kb + c,
              &bL[par][i * 2048 + wid * 512]);
    }
  };

  stage(0, 0);
  f32x4 acc[2][4] = {};
  for (int it = 0; it < nIter; ++it) {
    const int par = it & 1;
    asm volatile("s_waitcnt vmcnt(0)" ::: "memory");
    __builtin_amdgcn_s_barrier();
    asm volatile("" ::: "memory");
    if (it + 1 < nIter) stage(it + 1, par ^ 1);
    bf8 af[2][2], bfr[4][2];
#pragma unroll
    for (int i = 0; i < 2; ++i)
#pragma unroll
      for (int kk = 0; kk < 2; ++kk)
        af[i][kk] =
            *(const bf8*)&aL[par][(wr + i * 16 + l15) * 64 + kk * 32 + l4 * 8];
#pragma unroll
    for (int j = 0; j < 4; ++j)
#pragma unroll
      for (int kk = 0; kk < 2; ++kk)
        bfr[j][kk] =
            *(const bf8*)&bL[par][(wc + j * 16 + l15) * 64 + kk * 32 + l4 * 8];
#pragma unroll
    for (int kk = 0; kk < 2; ++kk)
#pragma unroll
      for (int i = 0; i < 2; ++i)
#pragma unroll
        for (int j = 0; j < 4; ++j)
          acc[i][j] = mfma16(af[i][kk], bfr[j][kk], acc[i][j]);
  }
#pragma unroll
  for (int i = 0; i < 2; ++i)
#pragma unroll
    for (int j = 0; j < 4; ++j)
#pragma unroll
      for (int r = 0; r < 4; ++r) {
        const size_t row = bm + wr + i * 16 + l4 * 4 + r;
        const size_t col = bn + wc + j * 16 + l15;
        if constexpr (OUT_BF16)
          ((ushort*)Cv)[row * N + col] = f2b(acc[i][j][r]);
        else
          ((float*)Cv)[row * N + col] = acc[i][j][r];
      }
}

// ---------------- Flash attention v13: 192-key (3-subtile) supersteps -----
// 512 blocks x 256 thr (4 waves = 4 heads of one kv group, shared KV stage).
// Pairing t = half ? 63-p : p (per-CU work sum = 33 tiles). Superstep = 3
// 64-key subtiles per barrier pair (48KB stage, single-buffered): vmcnt+bar,
// read ALL subtiles' frags, lgkm+bar, stage next superstep, 3x astep2.
// Per-CU sync sequences drop ~17 -> ~12. Fixed-max softmax (log2 domain).
#define MCONST 12.0f

__device__ __forceinline__ void astep2(const bf8 (&kfA)[4], const bf8 (&kfB)[4],
                                       const bf8 (&vfA)[4], const bf8 (&vfB)[4],
                                       const bf8 (&qf)[4], f32x16& o0,
                                       f32x16& o1, float& l, int k0, int qg,
                                       bool maskt, int hi) {
  f32x16 s0 = {}, s1 = {};
#pragma unroll
  for (int ks = 0; ks < 4; ++ks) s0 = mfma32(kfA[ks], qf[ks], s0);
#pragma unroll
  for (int ks = 0; ks < 4; ++ks) s1 = mfma32(kfB[ks], qf[ks], s1);
  if (maskt) {
#pragma unroll
    for (int r = 0; r < 16; ++r) {
      const int key = k0 + (r & 3) + 8 * (r >> 2) + 4 * hi;
      if (key > qg) s0[r] = -1e30f;
      if (key + 32 > qg) s1[r] = -1e30f;
    }
  }
  float t[16];
#pragma unroll
  for (int r = 0; r < 16; ++r) {
    s0[r] = fexp2(s0[r] - MCONST);
    s1[r] = fexp2(s1[r] - MCONST);
    t[r] = s0[r] + s1[r];
  }
#pragma unroll
  for (int st = 8; st > 0; st >>= 1)
#pragma unroll
    for (int r = 0; r < st; ++r) t[r] += t[r + st];
  l += t[0] + __shfl_xor(t[0], 32);
  bf8 pa[4];
  {
    uint a0 = cvtpk(s0[0], s0[1]), a1 = cvtpk(s0[2], s0[3]);
    uint b0 = cvtpk(s0[4], s0[5]), b1 = cvtpk(s0[6], s0[7]);
    plswap(a0, b0);
    plswap(a1, b1);
    i32x4 w = {(int)a0, (int)a1, (int)b0, (int)b1};
    pa[0] = __builtin_bit_cast(bf8, w);
    uint c0 = cvtpk(s0[8], s0[9]), c1 = cvtpk(s0[10], s0[11]);
    uint d0 = cvtpk(s0[12], s0[13]), d1 = cvtpk(s0[14], s0[15]);
    plswap(c0, d0);
    plswap(c1, d1);
    i32x4 w2 = {(int)c0, (int)c1, (int)d0, (int)d1};
    pa[1] = __builtin_bit_cast(bf8, w2);
  }
  {
    uint a0 = cvtpk(s1[0], s1[1]), a1 = cvtpk(s1[2], s1[3]);
    uint b0 = cvtpk(s1[4], s1[5]), b1 = cvtpk(s1[6], s1[7]);
    plswap(a0, b0);
    plswap(a1, b1);
    i32x4 w = {(int)a0, (int)a1, (int)b0, (int)b1};
    pa[2] = __builtin_bit_cast(bf8, w);
    uint c0 = cvtpk(s1[8], s1[9]), c1 = cvtpk(s1[10], s1[11]);
    uint d0 = cvtpk(s1[12], s1[13]), d1 = cvtpk(s1[14], s1[15]);
    plswap(c0, d0);
    plswap(c1, d1);
    i32x4 w2 = {(int)c0, (int)c1, (int)d0, (int)d1};
    pa[3] = __builtin_bit_cast(bf8, w2);
  }
#pragma unroll
  for (int ks = 0; ks < 4; ++ks) o0 = mfma32(vfA[ks], pa[ks], o0);
#pragma unroll
  for (int ks = 0; ks < 4; ++ks) o1 = mfma32(vfB[ks], pa[ks], o1);
}

__device__ __forceinline__ void tile_out(ushort* ow, const f32x16& o0,
                                         const f32x16& o1, float l, int b,
                                         int h, int qw, int l31, int hi,
                                         int lane, ushort* ao) {
  const float inv = 1.0f / l;
#pragma unroll
  for (int dt = 0; dt < 2; ++dt)
#pragma unroll
    for (int rq = 0; rq < 4; ++rq) {
      const f32x16& ac = dt ? o1 : o0;
      uint2 w;
      w.x = (uint)f2b(ac[rq * 4 + 0] * inv) |
            ((uint)f2b(ac[rq * 4 + 1] * inv) << 16);
      w.y = (uint)f2b(ac[rq * 4 + 2] * inv) |
            ((uint)f2b(ac[rq * 4 + 3] * inv) << 16);
      const int d = dt * 32 + 8 * rq + 4 * hi;
      *(uint2*)&ow[l31 * 66 + d] = w;
    }
  asm volatile("s_waitcnt lgkmcnt(0)" ::: "memory");
  __builtin_amdgcn_sched_barrier(0);
  const int rrow = lane >> 4;
  const int rcol = (lane & 15) * 4;
  const size_t gbase = ((size_t)b * 2048 + qw) * 1024 + h * 64;
#pragma unroll
  for (int i = 0; i < 8; ++i) {
    const int rw = i * 4 + rrow;
    uint2 v = *(const uint2*)&ow[rw * 66 + rcol];
    *(uint2*)&ao[gbase + (size_t)rw * 1024 + rcol] = v;
  }
}

__global__ __launch_bounds__(256) void attn_fwd(const ushort* __restrict__ qh,
                                                const ushort* __restrict__ kh,
                                                const ushort* __restrict__ vT,
                                                ushort* __restrict__ ao) {
  __shared__ ushort kls[3][4096];   // 3 x 8KB K subtiles (swizzled)
  __shared__ ushort vls[3][4096];   // 3 x 8KB V subtiles (swizzled)
  __shared__ ushort olds[4][2176];  // per-wave epilogue transpose scratch
  const int tid = threadIdx.x;
  const int wid = tid >> 6, lane = tid & 63;
  const int l31 = lane & 31, hi = lane >> 5;
  const int gid = blockIdx.x;  // 512
  const int bk = gid & 7;      // b*4 + kv (fixed per XCD -> KV L2-resident)
  const int b = bk >> 2, kv = bk & 3;
  const int rest = gid >> 3;   // 0..63
  const int p = rest & 31, half = rest >> 5;
  const int t = half ? (63 - p) : p;  // pairing: per-CU tile sum = 33
  const int h = kv * 4 + wid;
  const int n = (32 * t + 95) >> 6;   // 64-key tiles: 1..32
  const int nss = (n + 2) / 3;        // 192-key supersteps: 1..11
  const int qg = t * 32 + l31;

  const ushort* kbase = kh + (size_t)(b * 4 + kv) * 2048 * 64;
  const ushort* vbase = vT + (size_t)(b * 4 + kv) * 64 * 2048;

  auto stageTile = [&](int j, int hf) {
    const int k0 = j * 64;
#pragma unroll
    for (int jj2 = 0; jj2 < 2; ++jj2) {
      const int jj = wid + jj2 * 4;
      const int i = jj * 64 + lane;
      const int r = i >> 3, s = i & 7;
      const int sw = (s ^ (r & 7)) << 3;
      gload16(kbase + (size_t)(k0 + r) * 64 + sw, kls[hf] + jj * 512);
      gload16(vbase + (size_t)r * 2048 + k0 + sw, vls[hf] + jj * 512);
    }
  };
  auto stageSS = [&](int ss) {
    const int j0 = 3 * ss;
    const int j1 = (3 * ss + 1 < n) ? (3 * ss + 1) : (n - 1);
    const int j2 = (3 * ss + 2 < n) ? (3 * ss + 2) : (n - 1);
    stageTile(j0, 0);
    stageTile(j1, 1);  // clamped duplicates harmless (never consumed)
    stageTile(j2, 2);
  };

  stageSS(0);

  bf8 qf[4];
  {
    const ushort* qb = qh + ((size_t)(b * 16 + h) * 2048 + qg) * 64 + hi * 8;
#pragma unroll
    for (int ks = 0; ks < 4; ++ks) qf[ks] = *(const bf8*)(qb + ks * 16);
  }

  f32x16 o0 = {}, o1 = {};
  float l = 0.f;
  const int sw0 = l31 & 7;

  for (int ss = 0; ss < nss; ++ss) {
    asm volatile("s_waitcnt vmcnt(0)" ::: "memory");  // own loads done
    __builtin_amdgcn_s_barrier();                     // everyone's loads done
    asm volatile("" ::: "memory");
    bf8 kfA[3][4], kfB[3][4], vfA[3][4], vfB[3][4];
#pragma unroll
    for (int hf = 0; hf < 3; ++hf)
#pragma unroll
      for (int ks = 0; ks < 4; ++ks) {
        const int c2 = 2 * ks + hi;
        const int off = (c2 ^ sw0) << 3;
        kfA[hf][ks] = *(const bf8*)&kls[hf][l31 * 64 + off];
        kfB[hf][ks] = *(const bf8*)&kls[hf][(32 + l31) * 64 + off];
        vfA[hf][ks] = *(const bf8*)&vls[hf][l31 * 64 + off];
        vfB[hf][ks] = *(const bf8*)&vls[hf][(32 + l31) * 64 + off];
      }
    asm volatile("s_waitcnt lgkmcnt(0)" ::: "memory");
    __builtin_amdgcn_sched_barrier(0);
    __builtin_amdgcn_s_barrier();  // all reads drained -> safe overwrite
    if (ss + 1 < nss) stageSS(ss + 1);
    const int j0 = 3 * ss, j1 = 3 * ss + 1, j2 = 3 * ss + 2;
    astep2(kfA[0], kfB[0], vfA[0], vfB[0], qf, o0, o1, l, j0 * 64, qg,
           j0 == n - 1, hi);
    if (j1 < n)
      astep2(kfA[1], kfB[1], vfA[1], vfB[1], qf, o0, o1, l, j1 * 64, qg,
             j1 == n - 1, hi);
    if (j2 < n)
      astep2(kfA[2], kfB[2], vfA[2], vfB[2], qf, o0, o1, l, j2 * 64, qg,
             j2 == n - 1, hi);
  }
  tile_out(olds[wid], o0, o1, l, b, h, t * 32, l31, hi, lane, ao);
}

extern "C" void kernel_launch(void* const* d_in, const int* in_sizes, int n_in,
                              void* d_out, int out_size, void* d_ws,
                              size_t ws_size, hipStream_t stream) {
  (void)in_sizes; (void)n_in; (void)out_size; (void)ws_size;
  const float* x = (const float*)d_in[0];
  const float* wq = (const float*)d_in[1];
  const float* wk = (const float*)d_in[2];
  const float* wv = (const float*)d_in[3];
  const float* wo = (const float*)d_in[4];
  const float* fc = (const float*)d_in[5];
  const float* fs = (const float*)d_in[6];
  float* out = (float*)d_out;

  ushort* xb = (ushort*)d_ws;               // 4096x1024
  ushort* wqkvT = xb + 4194304;             // 1536x1024
  ushort* woT = wqkvT + 1572864;            // 1024x1024
  ushort* qkv = woT + 1048576;              // (unused now)
  ushort* qh = qkv + 6291456;               // 32x2048x64
  ushort* kh = qh + 4194304;                // 8x2048x64
  ushort* vTb = kh + 1048576;               // 8x64x2048
  ushort* ao = vTb + 1048576;               // 4096x1024

  prep1<<<6656, 256, 0, stream>>>(x, wq, wk, wv, wo, xb, wqkvT, woT);
  gemm_rope<<<768, 256, 0, stream>>>(xb, wqkvT, fc, fs, qh, kh, vTb);
  attn_fwd<<<512, 256, 0, stream>>>(qh, kh, vTb, ao);
  gemm_bt<false><<<512, 256, 0, stream>>>(ao, woT, out, 4096, 1024, 1024, 8);
}

// Round 24
// 96.578 us; speedup vs baseline: 1.0084x; 1.0084x over previous
//
#include <hip/hip_runtime.h>

typedef short bf8 __attribute__((ext_vector_type(8)));   // 8 bf16 in 4 VGPRs
typedef float f32x4 __attribute__((ext_vector_type(4)));
typedef float f32x16 __attribute__((ext_vector_type(16)));
typedef int i32x4 __attribute__((ext_vector_type(4)));

__device__ __forceinline__ ushort f2b(float f) {
  unsigned x = __builtin_bit_cast(unsigned, f);
  unsigned r = (x + 0x7fffu + ((x >> 16) & 1u)) >> 16;
  return (ushort)r;
}
__device__ __forceinline__ float b2f(ushort u) {
  unsigned x = ((unsigned)u) << 16;
  return __builtin_bit_cast(float, x);
}

__device__ __forceinline__ f32x4 mfma16(bf8 a, bf8 b, f32x4 c) {
  return __builtin_amdgcn_mfma_f32_16x16x32_bf16(a, b, c, 0, 0, 0);
}
__device__ __forceinline__ f32x16 mfma32(bf8 a, bf8 b, f32x16 c) {
  return __builtin_amdgcn_mfma_f32_32x32x16_bf16(a, b, c, 0, 0, 0);
}

__device__ __forceinline__ float fexp2(float x) {
#if __has_builtin(__builtin_amdgcn_exp2f)
  return __builtin_amdgcn_exp2f(x);
#else
  return exp2f(x);
#endif
}

__device__ __forceinline__ uint cvtpk(float lo, float hi_) {
  uint r;
  asm("v_cvt_pk_bf16_f32 %0, %1, %2" : "=v"(r) : "v"(lo), "v"(hi_));
  return r;
}
__device__ __forceinline__ void plswap(uint& a, uint& b) {
  asm("v_permlane32_swap_b32 %0, %1" : "+v"(a), "+v"(b));
}

__device__ __forceinline__ void gload16(const ushort* g, ushort* l) {
  __builtin_amdgcn_global_load_lds(
      (const __attribute__((address_space(1))) void*)g,
      (__attribute__((address_space(3))) void*)l, 16, 0, 0);
}

// ---------------- prep1: cast x (f32->bf16) + all weight transposes ------
__global__ __launch_bounds__(256) void prep1(
    const float* __restrict__ x, const float* __restrict__ wq,
    const float* __restrict__ wk, const float* __restrict__ wv,
    const float* __restrict__ wo, ushort* __restrict__ xb,
    ushort* __restrict__ wqkvT, ushort* __restrict__ woT) {
  __shared__ float tile[32][33];
  const int bid = blockIdx.x;
  if (bid < 4096) {
    const int i = (bid * 256 + threadIdx.x) * 4;
    float4 v = *(const float4*)(x + i);
    ushort4 o;
    o.x = f2b(v.x); o.y = f2b(v.y); o.z = f2b(v.z); o.w = f2b(v.w);
    *(ushort4*)(xb + i) = o;
    return;
  }
  int t = bid - 4096;  // 0..2559
  const float* src;
  ushort* dst;
  int N;
  if (t < 1024) {
    src = wq; dst = wqkvT; N = 1024;
  } else if (t < 1280) {
    src = wk; dst = wqkvT + 1024 * 1024; N = 256; t -= 1024;
  } else if (t < 1536) {
    src = wv; dst = wqkvT + 1280 * 1024; N = 256; t -= 1280;
  } else {
    src = wo; dst = woT; N = 1024; t -= 1536;
  }
  const int kx = (t & 31) * 32, nx = (t >> 5) * 32;
  const int tx = threadIdx.x & 31, ty = threadIdx.x >> 5;
#pragma unroll
  for (int i = ty; i < 32; i += 8)
    tile[i][tx] = src[(size_t)(kx + i) * N + nx + tx];
  __syncthreads();
#pragma unroll
  for (int i = ty; i < 32; i += 8)
    dst[(size_t)(nx + i) * 1024 + kx + tx] = f2b(tile[tx][i]);
}

// ------- gemm_rope: x @ wqkvT with FUSED RoPE + V-transpose epilogue ------
// 64x128 tile, BK=64, double-buffered, XCD-swizzled (768 blocks, nbx=12).
__global__ __launch_bounds__(256) void gemm_rope(
    const ushort* __restrict__ A, const ushort* __restrict__ Bt,
    const float* __restrict__ fc, const float* __restrict__ fs,
    ushort* __restrict__ qh, ushort* __restrict__ kh,
    ushort* __restrict__ vT) {
  __shared__ ushort aL[2][64 * 64];    // 2 x 8 KB
  __shared__ ushort bL[2][128 * 64];   // 2 x 16 KB (reused for V transpose)
  const int K = 1024;
  const int tid = threadIdx.x;
  const int wid = tid >> 6, lane = tid & 63;
  const int l15 = lane & 15, l4 = lane >> 4;
  const int qch = gridDim.x >> 3;
  const int sw = (blockIdx.x & 7) * qch + (blockIdx.x >> 3);
  const int bxi = sw % 12, byi = sw / 12;
  const int bm = byi * 64, bn = bxi * 128;
  const int wr = (wid & 1) * 32, wc = (wid >> 1) * 64;
  const int nIter = K >> 6;

  auto stage = [&](int it, int par) {
    const int kb = it * 64;
#pragma unroll
    for (int i = 0; i < 2; ++i) {
      const int e = (i * 256 + tid) * 8;
      const int r = e >> 6, c = e & 63;
      gload16(A + (size_t)(bm + r) * K + kb + c,
              &aL[par][i * 2048 + wid * 512]);
    }
#pragma unroll
    for (int i = 0; i < 4; ++i) {
      const int e = (i * 256 + tid) * 8;
      const int r = e >> 6, c = e & 63;
      gload16(Bt + (size_t)(bn + r) * K + kb + c,
              &bL[par][i * 2048 + wid * 512]);
    }
  };

  stage(0, 0);
  f32x4 acc[2][4] = {};
  for (int it = 0; it < nIter; ++it) {
    const int par = it & 1;
    asm volatile("s_waitcnt vmcnt(0)" ::: "memory");
    __builtin_amdgcn_s_barrier();
    asm volatile("" ::: "memory");
    if (it + 1 < nIter) stage(it + 1, par ^ 1);
    bf8 af[2][2], bfr[4][2];
#pragma unroll
    for (int i = 0; i < 2; ++i)
#pragma unroll
      for (int kk = 0; kk < 2; ++kk)
        af[i][kk] =
            *(const bf8*)&aL[par][(wr + i * 16 + l15) * 64 + kk * 32 + l4 * 8];
#pragma unroll
    for (int j = 0; j < 4; ++j)
#pragma unroll
      for (int kk = 0; kk < 2; ++kk)
        bfr[j][kk] =
            *(const bf8*)&bL[par][(wc + j * 16 + l15) * 64 + kk * 32 + l4 * 8];
#pragma unroll
    for (int kk = 0; kk < 2; ++kk)
#pragma unroll
      for (int i = 0; i < 2; ++i)
#pragma unroll
        for (int j = 0; j < 4; ++j)
          acc[i][j] = mfma16(af[i][kk], bfr[j][kk], acc[i][j]);
  }

  if (bxi < 10) {
    // ---- Q or K: fused RoPE, direct write ----
    const bool isQ = bxi < 8;
    const float qs = isQ ? 0.18033688f : 1.0f;  // (1/8)*log2(e) for Q
    const int colbase = bn + wc;
    const int head = isQ ? (colbase >> 6) : ((colbase - 1024) >> 6);
    const int nh = isQ ? 16 : 4;
    ushort* outp = isQ ? qh : kh;
#pragma unroll
    for (int i = 0; i < 2; ++i)
#pragma unroll
      for (int j = 0; j < 4; ++j) {
        const int d = j * 16 + l15;
        const int d2 = d >> 1;
#pragma unroll
        for (int r = 0; r < 4; ++r) {
          const int row = bm + wr + i * 16 + l4 * 4 + r;
          const int s = row & 2047, bb = row >> 11;
          const float c = fc[s * 32 + d2], sn = fs[s * 32 + d2];
          const float val = acc[i][j][r];
          const float par = __shfl_xor(val, 1);
          float o;
          if ((l15 & 1) == 0)
            o = (val * c - par * sn) * qs;  // even d: tr*c - ti*s
          else
            o = (par * sn + val * c) * qs;  // odd d: tr*s + ti*c
          outp[((size_t)(bb * nh + head) * 2048 + s) * 64 + d] = f2b(o);
        }
      }
  } else {
    // ---- V: LDS transpose (reuse bL, free after K-loop) then write vT ----
    __syncthreads();  // block-uniform branch; all frag reads already in regs
    ushort* ldsT = &bL[0][0];  // 128 x 68 ushorts = 17 KB <= 32 KB
#pragma unroll
    for (int i = 0; i < 2; ++i)
#pragma unroll
      for (int j = 0; j < 4; ++j) {
        const int cl = wc + j * 16 + l15;
#pragma unroll
        for (int r = 0; r < 4; ++r) {
          const int rl = wr + i * 16 + l4 * 4 + r;
          ldsT[cl * 68 + rl] = f2b(acc[i][j][r]);
        }
      }
    __syncthreads();
    const int bb = bm >> 11, sbase = bm & 2047;
    const int dl = tid >> 1, sh = (tid & 1) * 32;
    const int gcol = bn + dl - 1280;
    const int kv = gcol >> 6, d = gcol & 63;
    ushort* dst = vT + ((size_t)(bb * 4 + kv) * 64 + d) * 2048 + sbase + sh;
    const ushort* srcl = ldsT + dl * 68 + sh;
#pragma unroll
    for (int k = 0; k < 8; ++k)
      *(uint2*)(dst + k * 4) = *(const uint2*)(srcl + k * 4);
  }
}

// ------- GEMM C[M][N]=A[M][K]*Bt[N][K]^T; 64x128, BK=64, double-buffered --
template <bool OUT_BF16>
__global__ __launch_bounds__(256) void gemm_bt(const ushort* __restrict__ A,
                                               const ushort* __restrict__ Bt,
                                               void* __restrict__ Cv, int M,
                                               int N, int K, int nbx) {
  __shared__ ushort aL[2][64 * 64];    // 2 x 8 KB
  __shared__ ushort bL[2][128 * 64];   // 2 x 16 KB
  const int tid = threadIdx.x;
  const int wid = tid >> 6, lane = tid & 63;
  const int l15 = lane & 15, l4 = lane >> 4;
  const int qch = gridDim.x >> 3;
  const int sw = (blockIdx.x & 7) * qch + (blockIdx.x >> 3);
  const int bxi = sw % nbx, byi = sw / nbx;
  const int bm = byi * 64, bn = bxi * 128;
  const int wr = (wid & 1) * 32, wc = (wid >> 1) * 64;
  const int nIter = K >> 6;

  auto stage = [&](int it, int par) {
    const int kb = it * 64;
#pragma unroll
    for (int i = 0; i < 2; ++i) {
      const int e = (i * 256 + tid) * 8;
      const int r = e >> 6, c = e & 63;
      gload16(A + (size_t)(bm + r) * K + kb + c,
              &aL[par][i * 2048 + wid * 512]);
    }
#pragma unroll
    for (int i = 0; i < 4; ++i) {
      const int e = (i * 256 + tid) * 8;
      const int r = e >> 6, c = e & 63;
      gload16(Bt + (size_t)(bn + r) * K + kb + c,
              &bL[par][i * 2048 + wid * 512]);
    }
  };

  stage(0, 0);
  f32x4 acc[2][4] = {};
  for (int it = 0; it < nIter; ++it) {
    const int par = it & 1;
    asm volatile("s_waitcnt vmcnt(0)" ::: "memory");
    __builtin_amdgcn_s_barrier();
    asm volatile("" ::: "memory");
    if (it + 1 < nIter) stage(it + 1, par ^ 1);
    bf8 af[2][2], bfr[4][2];
#pragma unroll
    for (int i = 0; i < 2; ++i)
#pragma unroll
      for (int kk = 0; kk < 2; ++kk)
        af[i][kk] =
            *(const bf8*)&aL[par][(wr + i * 16 + l15) * 64 + kk * 32 + l4 * 8];
#pragma unroll
    for (int j = 0; j < 4; ++j)
#pragma unroll
      for (int kk = 0; kk < 2; ++kk)
        bfr[j][kk] =
            *(const bf8*)&bL[par][(wc + j * 16 + l15) * 64 + kk * 32 + l4 * 8];
#pragma unroll
    for (int kk = 0; kk < 2; ++kk)
#pragma unroll
      for (int i = 0; i < 2; ++i)
#pragma unroll
        for (int j = 0; j < 4; ++j)
          acc[i][j] = mfma16(af[i][kk], bfr[j][kk], acc[i][j]);
  }
#pragma unroll
  for (int i = 0; i < 2; ++i)
#pragma unroll
    for (int j = 0; j < 4; ++j)
#pragma unroll
      for (int r = 0; r < 4; ++r) {
        const size_t row = bm + wr + i * 16 + l4 * 4 + r;
        const size_t col = bn + wc + j * 16 + l15;
        if constexpr (OUT_BF16)
          ((ushort*)Cv)[row * N + col] = f2b(acc[i][j][r]);
        else
          ((float*)Cv)[row * N + col] = acc[i][j][r];
      }
}

// ---------------- Flash attention v11: 128-key supersteps (R22 best) ------
#define MCONST 12.0f

__device__ __forceinline__ void astep2(const bf8 (&kfA)[4], const bf8 (&kfB)[4],
                                       const bf8 (&vfA)[4], const bf8 (&vfB)[4],
                                       const bf8 (&qf)[4], f32x16& o0,
                                       f32x16& o1, float& l, int k0, int qg,
                                       bool maskt, int hi) {
  f32x16 s0 = {}, s1 = {};
#pragma unroll
  for (int ks = 0; ks < 4; ++ks) s0 = mfma32(kfA[ks], qf[ks], s0);
#pragma unroll
  for (int ks = 0; ks < 4; ++ks) s1 = mfma32(kfB[ks], qf[ks], s1);
  if (maskt) {
#pragma unroll
    for (int r = 0; r < 16; ++r) {
      const int key = k0 + (r & 3) + 8 * (r >> 2) + 4 * hi;
      if (key > qg) s0[r] = -1e30f;
      if (key + 32 > qg) s1[r] = -1e30f;
    }
  }
  float t[16];
#pragma unroll
  for (int r = 0; r < 16; ++r) {
    s0[r] = fexp2(s0[r] - MCONST);
    s1[r] = fexp2(s1[r] - MCONST);
    t[r] = s0[r] + s1[r];
  }
#pragma unroll
  for (int st = 8; st > 0; st >>= 1)
#pragma unroll
    for (int r = 0; r < st; ++r) t[r] += t[r + st];
  l += t[0] + __shfl_xor(t[0], 32);
  bf8 pa[4];
  {
    uint a0 = cvtpk(s0[0], s0[1]), a1 = cvtpk(s0[2], s0[3]);
    uint b0 = cvtpk(s0[4], s0[5]), b1 = cvtpk(s0[6], s0[7]);
    plswap(a0, b0);
    plswap(a1, b1);
    i32x4 w = {(int)a0, (int)a1, (int)b0, (int)b1};
    pa[0] = __builtin_bit_cast(bf8, w);
    uint c0 = cvtpk(s0[8], s0[9]), c1 = cvtpk(s0[10], s0[11]);
    uint d0 = cvtpk(s0[12], s0[13]), d1 = cvtpk(s0[14], s0[15]);
    plswap(c0, d0);
    plswap(c1, d1);
    i32x4 w2 = {(int)c0, (int)c1, (int)d0, (int)d1};
    pa[1] = __builtin_bit_cast(bf8, w2);
  }
  {
    uint a0 = cvtpk(s1[0], s1[1]), a1 = cvtpk(s1[2], s1[3]);
    uint b0 = cvtpk(s1[4], s1[5]), b1 = cvtpk(s1[6], s1[7]);
    plswap(a0, b0);
    plswap(a1, b1);
    i32x4 w = {(int)a0, (int)a1, (int)b0, (int)b1};
    pa[2] = __builtin_bit_cast(bf8, w);
    uint c0 = cvtpk(s1[8], s1[9]), c1 = cvtpk(s1[10], s1[11]);
    uint d0 = cvtpk(s1[12], s1[13]), d1 = cvtpk(s1[14], s1[15]);
    plswap(c0, d0);
    plswap(c1, d1);
    i32x4 w2 = {(int)c0, (int)c1, (int)d0, (int)d1};
    pa[3] = __builtin_bit_cast(bf8, w2);
  }
#pragma unroll
  for (int ks = 0; ks < 4; ++ks) o0 = mfma32(vfA[ks], pa[ks], o0);
#pragma unroll
  for (int ks = 0; ks < 4; ++ks) o1 = mfma32(vfB[ks], pa[ks], o1);
}

__device__ __forceinline__ void tile_out(ushort* ow, const f32x16& o0,
                                         const f32x16& o1, float l, int b,
                                         int h, int qw, int l31, int hi,
                                         int lane, ushort* ao) {
  const float inv = 1.0f / l;
#pragma unroll
  for (int dt = 0; dt < 2; ++dt)
#pragma unroll
    for (int rq = 0; rq < 4; ++rq) {
      const f32x16& ac = dt ? o1 : o0;
      uint2 w;
      w.x = (uint)f2b(ac[rq * 4 + 0] * inv) |
            ((uint)f2b(ac[rq * 4 + 1] * inv) << 16);
      w.y = (uint)f2b(ac[rq * 4 + 2] * inv) |
            ((uint)f2b(ac[rq * 4 + 3] * inv) << 16);
      const int d = dt * 32 + 8 * rq + 4 * hi;
      *(uint2*)&ow[l31 * 66 + d] = w;
    }
  asm volatile("s_waitcnt lgkmcnt(0)" ::: "memory");
  __builtin_amdgcn_sched_barrier(0);
  const int rrow = lane >> 4;
  const int rcol = (lane & 15) * 4;
  const size_t gbase = ((size_t)b * 2048 + qw) * 1024 + h * 64;
#pragma unroll
  for (int i = 0; i < 8; ++i) {
    const int rw = i * 4 + rrow;
    uint2 v = *(const uint2*)&ow[rw * 66 + rcol];
    *(uint2*)&ao[gbase + (size_t)rw * 1024 + rcol] = v;
  }
}

__global__ __launch_bounds__(256) void attn_fwd(const ushort* __restrict__ qh,
                                                const ushort* __restrict__ kh,
                                                const ushort* __restrict__ vT,
                                                ushort* __restrict__ ao) {
  __shared__ ushort kls[2][4096];   // 2 x 8KB K subtiles (swizzled)
  __shared__ ushort vls[2][4096];   // 2 x 8KB V subtiles (swizzled)
  __shared__ ushort olds[4][2176];  // per-wave epilogue transpose scratch
  const int tid = threadIdx.x;
  const int wid = tid >> 6, lane = tid & 63;
  const int l31 = lane & 31, hi = lane >> 5;
  const int gid = blockIdx.x;  // 512
  const int bk = gid & 7;      // b*4 + kv (fixed per XCD -> KV L2-resident)
  const int b = bk >> 2, kv = bk & 3;
  const int rest = gid >> 3;   // 0..63
  const int p = rest & 31, half = rest >> 5;
  const int t = half ? (63 - p) : p;  // pairing: per-CU tile sum = 33
  const int h = kv * 4 + wid;
  const int n = (32 * t + 95) >> 6;   // 64-key tiles: 1..32
  const int nss = (n + 1) >> 1;       // 128-key supersteps: 1..16
  const int qg = t * 32 + l31;

  const ushort* kbase = kh + (size_t)(b * 4 + kv) * 2048 * 64;
  const ushort* vbase = vT + (size_t)(b * 4 + kv) * 64 * 2048;

  auto stageTile = [&](int j, int hf) {
    const int k0 = j * 64;
#pragma unroll
    for (int jj2 = 0; jj2 < 2; ++jj2) {
      const int jj = wid + jj2 * 4;
      const int i = jj * 64 + lane;
      const int r = i >> 3, s = i & 7;
      const int sw = (s ^ (r & 7)) << 3;
      gload16(kbase + (size_t)(k0 + r) * 64 + sw, kls[hf] + jj * 512);
      gload16(vbase + (size_t)r * 2048 + k0 + sw, vls[hf] + jj * 512);
    }
  };
  auto stageSS = [&](int ss) {
    const int j0 = 2 * ss;
    const int j1 = (2 * ss + 1 < n) ? (2 * ss + 1) : (n - 1);
    stageTile(j0, 0);
    stageTile(j1, 1);
  };

  stageSS(0);

  bf8 qf[4];
  {
    const ushort* qb = qh + ((size_t)(b * 16 + h) * 2048 + qg) * 64 + hi * 8;
#pragma unroll
    for (int ks = 0; ks < 4; ++ks) qf[ks] = *(const bf8*)(qb + ks * 16);
  }

  f32x16 o0 = {}, o1 = {};
  float l = 0.f;
  const int sw0 = l31 & 7;

  for (int ss = 0; ss < nss; ++ss) {
    asm volatile("s_waitcnt vmcnt(0)" ::: "memory");
    __builtin_amdgcn_s_barrier();
    asm volatile("" ::: "memory");
    bf8 kfA[2][4], kfB[2][4], vfA[2][4], vfB[2][4];
#pragma unroll
    for (int hf = 0; hf < 2; ++hf)
#pragma unroll
      for (int ks = 0; ks < 4; ++ks) {
        const int c2 = 2 * ks + hi;
        const int off = (c2 ^ sw0) << 3;
        kfA[hf][ks] = *(const bf8*)&kls[hf][l31 * 64 + off];
        kfB[hf][ks] = *(const bf8*)&kls[hf][(32 + l31) * 64 + off];
        vfA[hf][ks] = *(const bf8*)&vls[hf][l31 * 64 + off];
        vfB[hf][ks] = *(const bf8*)&vls[hf][(32 + l31) * 64 + off];
      }
    asm volatile("s_waitcnt lgkmcnt(0)" ::: "memory");
    __builtin_amdgcn_sched_barrier(0);
    __builtin_amdgcn_s_barrier();  // all reads drained -> safe overwrite
    if (ss + 1 < nss) stageSS(ss + 1);
    const int j0 = 2 * ss, j1 = 2 * ss + 1;
    astep2(kfA[0], kfB[0], vfA[0], vfB[0], qf, o0, o1, l, j0 * 64, qg,
           j0 == n - 1, hi);
    if (j1 < n)
      astep2(kfA[1], kfB[1], vfA[1], vfB[1], qf, o0, o1, l, j1 * 64, qg,
             j1 == n - 1, hi);
  }
  tile_out(olds[wid], o0, o1, l, b, h, t * 32, l31, hi, lane, ao);
}

extern "C" void kernel_launch(void* const* d_in, const int* in_sizes, int n_in,
                              void* d_out, int out_size, void* d_ws,
                              size_t ws_size, hipStream_t stream) {
  (void)in_sizes; (void)n_in; (void)out_size; (void)ws_size;
  const float* x = (const float*)d_in[0];
  const float* wq = (const float*)d_in[1];
  const float* wk = (const float*)d_in[2];
  const float* wv = (const float*)d_in[3];
  const float* wo = (const float*)d_in[4];
  const float* fc = (const float*)d_in[5];
  const float* fs = (const float*)d_in[6];
  float* out = (float*)d_out;

  ushort* xb = (ushort*)d_ws;               // 4096x1024
  ushort* wqkvT = xb + 4194304;             // 1536x1024
  ushort* woT = wqkvT + 1572864;            // 1024x1024
  ushort* qkv = woT + 1048576;              // (unused now)
  ushort* qh = qkv + 6291456;               // 32x2048x64
  ushort* kh = qh + 4194304;                // 8x2048x64
  ushort* vTb = kh + 1048576;               // 8x64x2048
  ushort* ao = vTb + 1048576;               // 4096x1024

  prep1<<<6656, 256, 0, stream>>>(x, wq, wk, wv, wo, xb, wqkvT, woT);
  gemm_rope<<<768, 256, 0, stream>>>(xb, wqkvT, fc, fs, qh, kh, vTb);
  attn_fwd<<<512, 256, 0, stream>>>(qh, kh, vTb, ao);
  gemm_bt<false><<<512, 256, 0, stream>>>(ao, woT, out, 4096, 1024, 1024, 8);
}